// Round 8
// baseline (361.655 us; speedup 1.0000x reference)
//
#include <hip/hip_runtime.h>
#include <hip/hip_bf16.h>

// Problem constants (reference: B,K,N,F,H = 20000,10,100000,256,128)
constexpr int B_ = 20000;
constexpr int K_ = 10;
constexpr int N_ = 100000;
constexpr int F_ = 256;
constexpr int H_ = 128;
constexpr int RW = 3 * H_;  // interleaved qkv row width (384 ushorts = 768 B)

typedef __attribute__((ext_vector_type(8))) short bf16x8;
typedef __attribute__((ext_vector_type(4))) float f32x4;

__device__ __forceinline__ unsigned short f2bf(float x) {
  unsigned int u = __builtin_bit_cast(unsigned int, x);
  unsigned int r = u + 0x7fffu + ((u >> 16) & 1u);
  return (unsigned short)(r >> 16);
}

__device__ __forceinline__ float bf2f(unsigned int u16) {
  return __builtin_bit_cast(float, u16 << 16);
}

// RNE pack of two f32 -> 2xbf16 in one dword (lo -> [15:0], hi -> [31:16]).
__device__ __forceinline__ unsigned int cvt_pk_bf16(float lo, float hi) {
  unsigned int r;
  asm("v_cvt_pk_bf16_f32 %0, %1, %2" : "=v"(r) : "v"(lo), "v"(hi));
  return r;
}

__device__ __forceinline__ float fast_tanh(float x) {
  float e = __expf(2.0f * x);
  return 1.0f - 2.0f * __builtin_amdgcn_rcpf(e + 1.0f);
}

// ---------------------------------------------------------------------------
// Prep: weights -> fragment-major bf16 layout (proven correct; unchanged).
// wat2 chunks (p, ks∈8, c∈8), 512 bf16 each: elem(lane,j) = Wa_p[32ks+8(lane>>4)+j][16c+(lane&15)]
// wbt2 chunks (p, c2∈8, ks2∈4):              elem(lane,j) = Wb_p[32ks2+8(lane>>4)+j][16c2+(lane&15)]
// ---------------------------------------------------------------------------
__global__ __launch_bounds__(256) void prep_kernel(
    const float* __restrict__ W1a, const float* __restrict__ W1b,
    const float* __restrict__ W2a, const float* __restrict__ W2b,
    const float* __restrict__ W3a, const float* __restrict__ W3b,
    unsigned short* __restrict__ wat2, unsigned short* __restrict__ wbt2) {
  const float* Wa[3] = {W1a, W2a, W3a};
  const float* Wb[3] = {W1b, W2b, W3b};
  int g = blockIdx.x * 256 + threadIdx.x;
  if (g < 3 * 64 * 512) {
    int chunk = g >> 9;
    int e = g & 511;
    int lane = e >> 3, j = e & 7;
    int c = chunk & 7;
    int ks = (chunk >> 3) & 7;
    int p = chunk >> 6;
    int k = 32 * ks + 8 * (lane >> 4) + j;
    int h = 16 * c + (lane & 15);
    wat2[g] = f2bf(Wa[p][k * H_ + h]);
  } else {
    int g2 = g - 3 * 64 * 512;
    int chunk = g2 >> 9;
    int e = g2 & 511;
    int lane = e >> 3, j = e & 7;
    int ks2 = chunk & 3;
    int c2 = (chunk >> 2) & 7;
    int p = chunk >> 5;
    int k = 32 * ks2 + 8 * (lane >> 4) + j;
    int h2 = 16 * c2 + (lane & 15);
    wbt2[g2] = f2bf(Wb[p][k * H_ + h2]);
  }
}

// ---------------------------------------------------------------------------
// Projections — R8: ZERO-BARRIER restructure. Evidence: 7 rounds, occupancy
// 25->71%, LDS/ILP/barrier-type changes — proj pinned 89-100us, all pipes
// <25% busy; wave residency ~23us vs ~1us of dependent work => waves park
// at __syncthreads (lockstep phase-latency serialization, m97-style).
// New structure: each WAVE is self-contained, handles 32 nodes (2 MFMA
// col-tiles), computes ALL 8 h-tiles (so layer-2's K=128 needs no other
// wave's data):
//   * layer-1 B-frags loaded DIRECTLY from E (2 float4 + cvt_pk per frag;
//     no xs stage, no stage barrier);
//   * layer1->layer2 transpose via PER-WAVE LDS scratch [32][68] dwords
//     (dword idx = h/2 = 8hp+2q+e; read back b128 at 16ks2+4q; +68 pad
//     de-stripes banks). Intra-wave LDS: NO barrier, lgkmcnt orders it.
//   * weights re-read per wave (288KB x 3125 waves ~ 0.9GB L2, ~26us
//     aggregate, overlappable) — the price of independence.
// No __syncthreads anywhere in this kernel.
// ---------------------------------------------------------------------------
constexpr int WAVES = 4;
constexpr int NPW = 32;             // nodes per wave
constexpr int MT = WAVES * NPW;     // 128 nodes per block
constexpr int SPAD = 68;            // dwords per node row in scratch (64+4 pad)

__global__ __launch_bounds__(256) void proj_kernel(
    const float* __restrict__ E,
    const unsigned short* __restrict__ wat2,
    const unsigned short* __restrict__ wbt2,
    unsigned short* __restrict__ qkvI) {
  __shared__ unsigned int sc[WAVES * NPW * SPAD];  // 34816 B

  const int tid = threadIdx.x;
  const int lane = tid & 63;
  const int w = tid >> 6;
  const int l15 = lane & 15;
  const int q = lane >> 4;

  const int base0 = blockIdx.x * MT + w * NPW;  // wave's first node
  int n0 = base0 + l15;       if (n0 >= N_) n0 = N_ - 1;
  int n1 = base0 + 16 + l15;  if (n1 >= N_) n1 = N_ - 1;
  unsigned int* scw = sc + w * (NPW * SPAD);

  const float* __restrict__ e0 = E + (size_t)n0 * F_ + 8 * q;
  const float* __restrict__ e1 = E + (size_t)n1 * F_ + 8 * q;

  for (int p = 0; p < 3; ++p) {
    const unsigned short* __restrict__ wa = wat2 + p * (64 * 512);
    const unsigned short* __restrict__ wb = wbt2 + p * (32 * 512);

    // ---- layer 1, K=256: acc[hp][nt]. B-frags straight from E.
    f32x4 acc[8][2];
#pragma unroll
    for (int hp = 0; hp < 8; ++hp) {
      acc[hp][0] = (f32x4)0.0f;
      acc[hp][1] = (f32x4)0.0f;
    }

#pragma unroll
    for (int ks = 0; ks < 8; ++ks) {
      // B-frag: lane (l15,q) holds X[node][32ks+8q+j], j=0..7
      float4 v0a = *(const float4*)(e0 + 32 * ks);
      float4 v0b = *(const float4*)(e0 + 32 * ks + 4);
      float4 v1a = *(const float4*)(e1 + 32 * ks);
      float4 v1b = *(const float4*)(e1 + 32 * ks + 4);
      union { unsigned int u[4]; bf16x8 v; } b0, b1;
      b0.u[0] = cvt_pk_bf16(v0a.x, v0a.y);
      b0.u[1] = cvt_pk_bf16(v0a.z, v0a.w);
      b0.u[2] = cvt_pk_bf16(v0b.x, v0b.y);
      b0.u[3] = cvt_pk_bf16(v0b.z, v0b.w);
      b1.u[0] = cvt_pk_bf16(v1a.x, v1a.y);
      b1.u[1] = cvt_pk_bf16(v1a.z, v1a.w);
      b1.u[2] = cvt_pk_bf16(v1b.x, v1b.y);
      b1.u[3] = cvt_pk_bf16(v1b.z, v1b.w);
#pragma unroll
      for (int hp = 0; hp < 8; ++hp) {
        bf16x8 a = *(const bf16x8*)&wa[(ks * 8 + hp) * 512 + lane * 8];
        acc[hp][0] = __builtin_amdgcn_mfma_f32_16x16x32_bf16(a, b0.v, acc[hp][0], 0, 0, 0);
        acc[hp][1] = __builtin_amdgcn_mfma_f32_16x16x32_bf16(a, b1.v, acc[hp][1], 0, 0, 0);
      }
    }

    // ---- tanh + pack -> per-wave scratch (no barrier: intra-wave only).
    // value (h = 16hp+4q+r, node col l15, tile nt) -> dword idx h/2 = 8hp+2q+e
#pragma unroll
    for (int nt = 0; nt < 2; ++nt)
#pragma unroll
      for (int hp = 0; hp < 8; ++hp) {
        unsigned int lo = cvt_pk_bf16(fast_tanh(acc[hp][nt][0]), fast_tanh(acc[hp][nt][1]));
        unsigned int hi = cvt_pk_bf16(fast_tanh(acc[hp][nt][2]), fast_tanh(acc[hp][nt][3]));
        *(uint2*)&scw[(nt * 16 + l15) * SPAD + 8 * hp + 2 * q] = make_uint2(lo, hi);
      }

    // ---- layer 2, K=128: B-frags read back from scratch (b128, aligned).
    f32x4 ac2[8][2];
#pragma unroll
    for (int c2 = 0; c2 < 8; ++c2) {
      ac2[c2][0] = (f32x4)0.0f;
      ac2[c2][1] = (f32x4)0.0f;
    }

#pragma unroll
    for (int ks2 = 0; ks2 < 4; ++ks2) {
      // lane (l15,q) holds T[node][32ks2+8q+j] = dwords [16ks2+4q .. +3]
      bf16x8 t0 = *(const bf16x8*)&scw[(l15)*SPAD + 16 * ks2 + 4 * q];
      bf16x8 t1 = *(const bf16x8*)&scw[(16 + l15) * SPAD + 16 * ks2 + 4 * q];
#pragma unroll
      for (int c2 = 0; c2 < 8; ++c2) {
        bf16x8 ab = *(const bf16x8*)&wb[(c2 * 4 + ks2) * 512 + lane * 8];
        ac2[c2][0] = __builtin_amdgcn_mfma_f32_16x16x32_bf16(ab, t0, ac2[c2][0], 0, 0, 0);
        ac2[c2][1] = __builtin_amdgcn_mfma_f32_16x16x32_bf16(ab, t1, ac2[c2][1], 0, 0, 0);
      }
    }

    // ---- store qkv^T: (h2 = 16c2+4q+r, node) -> 8B contiguous stores
#pragma unroll
    for (int nt = 0; nt < 2; ++nt)
#pragma unroll
      for (int c2 = 0; c2 < 8; ++c2) {
        int n = base0 + nt * 16 + l15;
        if (n < N_) {
          unsigned int lo = cvt_pk_bf16(ac2[c2][nt][0], ac2[c2][nt][1]);
          unsigned int hi = cvt_pk_bf16(ac2[c2][nt][2], ac2[c2][nt][3]);
          *(uint2*)&qkvI[(size_t)n * RW + p * H_ + 16 * c2 + 4 * q] =
              make_uint2(lo, hi);
        }
      }
  }
}

// ---------------------------------------------------------------------------
// Phase 2: one WAVE per batch node, gathering from interleaved qkvI
// (768 B contiguous per neighbor). No LDS, no barriers. (Unchanged.)
// ---------------------------------------------------------------------------
__global__ __launch_bounds__(256) void agg_kernel(
    const int* __restrict__ nbr,
    const unsigned short* __restrict__ qkvI,
    float* __restrict__ out) {
  const int lane = threadIdx.x & 63;
  const int wv = threadIdx.x >> 6;
  const int b = blockIdx.x * 4 + wv;
  const int l15 = lane & 15;
  const int kg = lane >> 4;

  const int ni = nbr[b * K_ + (l15 < K_ ? l15 : 0)];
  const size_t nbase = (size_t)ni * RW;

  // scores[i][j] = q_i . k_j
  f32x4 sc = (f32x4)0.0f;
#pragma unroll
  for (int k = 0; k < 4; ++k) {
    const int off = k * 32 + kg * 8;
    bf16x8 qf = *(const bf16x8*)&qkvI[nbase + off];
    bf16x8 kf = *(const bf16x8*)&qkvI[nbase + H_ + off];
    sc = __builtin_amdgcn_mfma_f32_16x16x32_bf16(qf, kf, sc, 0, 0, 0);
  }

  if (l15 >= K_) {
#pragma unroll
    for (int r = 0; r < 4; ++r) sc[r] = -3.0e38f;
  }

  float mx[4], e[4], sm[4];
#pragma unroll
  for (int r = 0; r < 4; ++r) mx[r] = sc[r];
#pragma unroll
  for (int st = 1; st < 16; st <<= 1)
#pragma unroll
    for (int r = 0; r < 4; ++r) mx[r] = fmaxf(mx[r], __shfl_xor(mx[r], st, 16));
#pragma unroll
  for (int r = 0; r < 4; ++r) { e[r] = __expf(sc[r] - mx[r]); sm[r] = e[r]; }
#pragma unroll
  for (int st = 1; st < 16; st <<= 1)
#pragma unroll
    for (int r = 0; r < 4; ++r) sm[r] += __shfl_xor(sm[r], st, 16);

  float cs = 0.0f;
#pragma unroll
  for (int r = 0; r < 4; ++r) {
    float a = e[r] * __builtin_amdgcn_rcpf(sm[r]);
    if (kg * 4 + r >= K_) a = 0.0f;
    cs += a;
  }
  cs += __shfl_xor(cs, 16, 64);
  cs += __shfl_xor(cs, 32, 64);

  float o0 = 0.0f, o1 = 0.0f;
#pragma unroll
  for (int j = 0; j < K_; ++j) {
    const float cj = __shfl(cs, j, 64);
    const int nj = __shfl(ni, j, 64);
    const unsigned int v2 =
        *(const unsigned int*)&qkvI[(size_t)nj * RW + 2 * H_ + 2 * lane];
    o0 = fmaf(cj, bf2f(v2 & 0xffffu), o0);
    o1 = fmaf(cj, bf2f(v2 >> 16), o1);
  }
  *(float2*)&out[(size_t)b * H_ + 2 * lane] = make_float2(o0, o1);
}

extern "C" void kernel_launch(void* const* d_in, const int* in_sizes, int n_in,
                              void* d_out, int out_size, void* d_ws, size_t ws_size,
                              hipStream_t stream) {
  const int* nbr = (const int*)d_in[0];
  const float* E = (const float*)d_in[1];
  const float* W1a = (const float*)d_in[2];
  const float* W1b = (const float*)d_in[3];
  const float* W2a = (const float*)d_in[4];
  const float* W2b = (const float*)d_in[5];
  const float* W3a = (const float*)d_in[6];
  const float* W3b = (const float*)d_in[7];
  float* out = (float*)d_out;

  // workspace: qkvI [N][384] bf16 interleaved = 76.8 MB, then frag-major weights
  unsigned short* qkvI = (unsigned short*)d_ws;
  unsigned short* wat2 = qkvI + (size_t)N_ * RW;
  unsigned short* wbt2 = wat2 + (size_t)3 * 64 * 512;

  prep_kernel<<<(3 * 64 * 512 + 3 * 32 * 512) / 256, 256, 0, stream>>>(
      W1a, W1b, W2a, W2b, W3a, W3b, wat2, wbt2);
  proj_kernel<<<(N_ + MT - 1) / MT, 256, 0, stream>>>(E, wat2, wbt2, qkvI);
  agg_kernel<<<B_ / 4, 256, 0, stream>>>(nbr, qkvI, out);
}

// Round 9
// 355.072 us; speedup vs baseline: 1.0185x; 1.0185x over previous
//
#include <hip/hip_runtime.h>
#include <hip/hip_bf16.h>

// Problem constants (reference: B,K,N,F,H = 20000,10,100000,256,128)
constexpr int B_ = 20000;
constexpr int K_ = 10;
constexpr int N_ = 100000;
constexpr int F_ = 256;
constexpr int H_ = 128;
constexpr int RW = 3 * H_;  // interleaved qkv row width (384 ushorts = 768 B)

typedef __attribute__((ext_vector_type(8))) short bf16x8;
typedef __attribute__((ext_vector_type(4))) float f32x4;

__device__ __forceinline__ unsigned short f2bf(float x) {
  unsigned int u = __builtin_bit_cast(unsigned int, x);
  unsigned int r = u + 0x7fffu + ((u >> 16) & 1u);
  return (unsigned short)(r >> 16);
}

__device__ __forceinline__ float bf2f(unsigned int u16) {
  return __builtin_bit_cast(float, u16 << 16);
}

// RNE pack of two f32 -> 2xbf16 in one dword (lo -> [15:0], hi -> [31:16]).
__device__ __forceinline__ unsigned int cvt_pk_bf16(float lo, float hi) {
  unsigned int r;
  asm("v_cvt_pk_bf16_f32 %0, %1, %2" : "=v"(r) : "v"(lo), "v"(hi));
  return r;
}

__device__ __forceinline__ float fast_tanh(float x) {
  float e = __expf(2.0f * x);
  return 1.0f - 2.0f * __builtin_amdgcn_rcpf(e + 1.0f);
}

// ---------------------------------------------------------------------------
// Prep: weights -> fragment-major bf16 layout (proven correct; unchanged).
// wat2 chunks (p, ks∈8, c∈8), 512 bf16 each: elem(lane,j) = Wa_p[32ks+8(lane>>4)+j][16c+(lane&15)]
// wbt2 chunks (p, c2∈8, ks2∈4):              elem(lane,j) = Wb_p[32ks2+8(lane>>4)+j][16c2+(lane&15)]
// ---------------------------------------------------------------------------
__global__ __launch_bounds__(256) void prep_kernel(
    const float* __restrict__ W1a, const float* __restrict__ W1b,
    const float* __restrict__ W2a, const float* __restrict__ W2b,
    const float* __restrict__ W3a, const float* __restrict__ W3b,
    unsigned short* __restrict__ wat2, unsigned short* __restrict__ wbt2) {
  const float* Wa[3] = {W1a, W2a, W3a};
  const float* Wb[3] = {W1b, W2b, W3b};
  int g = blockIdx.x * 256 + threadIdx.x;
  if (g < 3 * 64 * 512) {
    int chunk = g >> 9;
    int e = g & 511;
    int lane = e >> 3, j = e & 7;
    int c = chunk & 7;
    int ks = (chunk >> 3) & 7;
    int p = chunk >> 6;
    int k = 32 * ks + 8 * (lane >> 4) + j;
    int h = 16 * c + (lane & 15);
    wat2[g] = f2bf(Wa[p][k * H_ + h]);
  } else {
    int g2 = g - 3 * 64 * 512;
    int chunk = g2 >> 9;
    int e = g2 & 511;
    int lane = e >> 3, j = e & 7;
    int ks2 = chunk & 3;
    int c2 = (chunk >> 2) & 7;
    int p = chunk >> 5;
    int k = 32 * ks2 + 8 * (lane >> 4) + j;
    int h2 = 16 * c2 + (lane & 15);
    wbt2[g2] = f2bf(Wb[p][k * H_ + h2]);
  }
}

// ---------------------------------------------------------------------------
// Projections — R9: staged-X + zero-barrier per-wave independence.
// R8 post-mortem: per-wave structure was CORRECT (passed) but E-direct
// B-frag reads were a 16-row scatter re-read 3x -> FETCH 52->138 MB, 226us.
// R9 keeps R8's wave-private pipeline and restores the proven coalesced
// stage: ONE WAVE PER BLOCK (64 thr), 32 nodes/wave:
//   * wave stages its own 32 E rows to private xs (1 row = 1 float4/lane
//     instruction, perfectly coalesced, read once) — no barrier, same wave;
//   * layer-1: acc[8][2], weight frags reused across both 16-node halves;
//     bx via conflict-free ds_read_b128 (R1's proven pattern, 4*(l15+q)%32
//     spreads 8 groups x 8 lanes = natural 8-phase);
//   * C->A transpose via per-wave scratch [16][68] dwords, half-at-a-time
//     (R8's verified mapping: dword idx h/2 = 8hp+2q+e; read 16ks2+4q);
//   * layer-2 + stores as R8 (verified).
// ZERO __syncthreads in this kernel. LDS 21.25 KB -> 7 blocks/CU; 3125
// fully independent waves. Weight L2 traffic ~0.9 GB (~26us aggregate) is
// the accepted price of independence.
// ---------------------------------------------------------------------------
constexpr int NPW = 32;     // nodes per wave (= per block)
constexpr int XS = F_ + 8;  // 264 shorts = 528 B row stride
constexpr int SPAD = 68;    // dwords per scratch row (64 + 4 pad)

__global__ __launch_bounds__(64) void proj_kernel(
    const float* __restrict__ E,
    const unsigned short* __restrict__ wat2,
    const unsigned short* __restrict__ wbt2,
    unsigned short* __restrict__ qkvI) {
  __shared__ unsigned short xs[NPW * XS];  // 16896 B
  __shared__ unsigned int scw[16 * SPAD];  // 4352 B (one 16-node half)

  const int lane = threadIdx.x;  // 0..63
  const int l15 = lane & 15;
  const int q = lane >> 4;
  const int base0 = blockIdx.x * NPW;

  // ---- stage this wave's 32 E rows (fp32 -> bf16), one row per load instr.
  {
    const float4* Eg = (const float4*)E;
#pragma unroll 4
    for (int r = 0; r < NPW; ++r) {
      int row = base0 + r;
      if (row >= N_) row = N_ - 1;
      float4 v = Eg[(size_t)row * (F_ / 4) + lane];
      *(uint2*)&xs[r * XS + lane * 4] =
          make_uint2(cvt_pk_bf16(v.x, v.y), cvt_pk_bf16(v.z, v.w));
    }
  }
  // no barrier: producer wave == consumer wave (lgkmcnt orders LDS ops).

  for (int p = 0; p < 3; ++p) {
    const unsigned short* __restrict__ wa = wat2 + p * (64 * 512);
    const unsigned short* __restrict__ wb = wbt2 + p * (32 * 512);

    // ---- layer 1, K=256: acc[hp][nt]; weight frags reused for both halves.
    f32x4 acc[8][2];
#pragma unroll
    for (int hp = 0; hp < 8; ++hp) {
      acc[hp][0] = (f32x4)0.0f;
      acc[hp][1] = (f32x4)0.0f;
    }

#pragma unroll
    for (int ks = 0; ks < 8; ++ks) {
      bf16x8 bx0 = *(const bf16x8*)&xs[(l15)*XS + 32 * ks + 8 * q];
      bf16x8 bx1 = *(const bf16x8*)&xs[(16 + l15) * XS + 32 * ks + 8 * q];
#pragma unroll
      for (int hp = 0; hp < 8; ++hp) {
        bf16x8 a = *(const bf16x8*)&wa[(ks * 8 + hp) * 512 + lane * 8];
        acc[hp][0] = __builtin_amdgcn_mfma_f32_16x16x32_bf16(a, bx0, acc[hp][0], 0, 0, 0);
        acc[hp][1] = __builtin_amdgcn_mfma_f32_16x16x32_bf16(a, bx1, acc[hp][1], 0, 0, 0);
      }
    }

    // ---- per 16-node half: transpose -> layer 2 -> store
#pragma unroll
    for (int nt = 0; nt < 2; ++nt) {
      // tanh + pack -> scratch. (h = 16hp+4q+r, node col l15) -> dword 8hp+2q+e
#pragma unroll
      for (int hp = 0; hp < 8; ++hp) {
        unsigned int lo = cvt_pk_bf16(fast_tanh(acc[hp][nt][0]), fast_tanh(acc[hp][nt][1]));
        unsigned int hi = cvt_pk_bf16(fast_tanh(acc[hp][nt][2]), fast_tanh(acc[hp][nt][3]));
        *(uint2*)&scw[l15 * SPAD + 8 * hp + 2 * q] = make_uint2(lo, hi);
      }
      // (compiler orders scratch write->read via lgkmcnt; same wave)

      // layer 2, K=128: ac2[c2] for this half.
      f32x4 ac2[8];
#pragma unroll
      for (int c2 = 0; c2 < 8; ++c2) ac2[c2] = (f32x4)0.0f;

#pragma unroll
      for (int ks2 = 0; ks2 < 4; ++ks2) {
        // lane (l15,q) holds T[node l15][32ks2+8q+j] = dwords 16ks2+4q..+3
        bf16x8 t = *(const bf16x8*)&scw[l15 * SPAD + 16 * ks2 + 4 * q];
#pragma unroll
        for (int c2 = 0; c2 < 8; ++c2) {
          bf16x8 ab = *(const bf16x8*)&wb[(c2 * 4 + ks2) * 512 + lane * 8];
          ac2[c2] = __builtin_amdgcn_mfma_f32_16x16x32_bf16(ab, t, ac2[c2], 0, 0, 0);
        }
      }

      // store qkv^T: (h2 = 16c2+4q+r, node) -> 8B contiguous stores
#pragma unroll
      for (int c2 = 0; c2 < 8; ++c2) {
        int n = base0 + nt * 16 + l15;
        if (n < N_) {
          unsigned int lo = cvt_pk_bf16(ac2[c2][0], ac2[c2][1]);
          unsigned int hi = cvt_pk_bf16(ac2[c2][2], ac2[c2][3]);
          *(uint2*)&qkvI[(size_t)n * RW + p * H_ + 16 * c2 + 4 * q] =
              make_uint2(lo, hi);
        }
      }
    }
  }
}

// ---------------------------------------------------------------------------
// Phase 2: one WAVE per batch node, gathering from interleaved qkvI
// (768 B contiguous per neighbor). No LDS, no barriers. (Unchanged.)
// ---------------------------------------------------------------------------
__global__ __launch_bounds__(256) void agg_kernel(
    const int* __restrict__ nbr,
    const unsigned short* __restrict__ qkvI,
    float* __restrict__ out) {
  const int lane = threadIdx.x & 63;
  const int wv = threadIdx.x >> 6;
  const int b = blockIdx.x * 4 + wv;
  const int l15 = lane & 15;
  const int kg = lane >> 4;

  const int ni = nbr[b * K_ + (l15 < K_ ? l15 : 0)];
  const size_t nbase = (size_t)ni * RW;

  // scores[i][j] = q_i . k_j
  f32x4 sc = (f32x4)0.0f;
#pragma unroll
  for (int k = 0; k < 4; ++k) {
    const int off = k * 32 + kg * 8;
    bf16x8 qf = *(const bf16x8*)&qkvI[nbase + off];
    bf16x8 kf = *(const bf16x8*)&qkvI[nbase + H_ + off];
    sc = __builtin_amdgcn_mfma_f32_16x16x32_bf16(qf, kf, sc, 0, 0, 0);
  }

  if (l15 >= K_) {
#pragma unroll
    for (int r = 0; r < 4; ++r) sc[r] = -3.0e38f;
  }

  float mx[4], e[4], sm[4];
#pragma unroll
  for (int r = 0; r < 4; ++r) mx[r] = sc[r];
#pragma unroll
  for (int st = 1; st < 16; st <<= 1)
#pragma unroll
    for (int r = 0; r < 4; ++r) mx[r] = fmaxf(mx[r], __shfl_xor(mx[r], st, 16));
#pragma unroll
  for (int r = 0; r < 4; ++r) { e[r] = __expf(sc[r] - mx[r]); sm[r] = e[r]; }
#pragma unroll
  for (int st = 1; st < 16; st <<= 1)
#pragma unroll
    for (int r = 0; r < 4; ++r) sm[r] += __shfl_xor(sm[r], st, 16);

  float cs = 0.0f;
#pragma unroll
  for (int r = 0; r < 4; ++r) {
    float a = e[r] * __builtin_amdgcn_rcpf(sm[r]);
    if (kg * 4 + r >= K_) a = 0.0f;
    cs += a;
  }
  cs += __shfl_xor(cs, 16, 64);
  cs += __shfl_xor(cs, 32, 64);

  float o0 = 0.0f, o1 = 0.0f;
#pragma unroll
  for (int j = 0; j < K_; ++j) {
    const float cj = __shfl(cs, j, 64);
    const int nj = __shfl(ni, j, 64);
    const unsigned int v2 =
        *(const unsigned int*)&qkvI[(size_t)nj * RW + 2 * H_ + 2 * lane];
    o0 = fmaf(cj, bf2f(v2 & 0xffffu), o0);
    o1 = fmaf(cj, bf2f(v2 >> 16), o1);
  }
  *(float2*)&out[(size_t)b * H_ + 2 * lane] = make_float2(o0, o1);
}

extern "C" void kernel_launch(void* const* d_in, const int* in_sizes, int n_in,
                              void* d_out, int out_size, void* d_ws, size_t ws_size,
                              hipStream_t stream) {
  const int* nbr = (const int*)d_in[0];
  const float* E = (const float*)d_in[1];
  const float* W1a = (const float*)d_in[2];
  const float* W1b = (const float*)d_in[3];
  const float* W2a = (const float*)d_in[4];
  const float* W2b = (const float*)d_in[5];
  const float* W3a = (const float*)d_in[6];
  const float* W3b = (const float*)d_in[7];
  float* out = (float*)d_out;

  // workspace: qkvI [N][384] bf16 interleaved = 76.8 MB, then frag-major weights
  unsigned short* qkvI = (unsigned short*)d_ws;
  unsigned short* wat2 = qkvI + (size_t)N_ * RW;
  unsigned short* wbt2 = wat2 + (size_t)3 * 64 * 512;

  prep_kernel<<<(3 * 64 * 512 + 3 * 32 * 512) / 256, 256, 0, stream>>>(
      W1a, W1b, W2a, W2b, W3a, W3b, wat2, wbt2);
  proj_kernel<<<(N_ + NPW - 1) / NPW, 64, 0, stream>>>(E, wat2, wbt2, qkvI);
  agg_kernel<<<B_ / 4, 256, 0, stream>>>(nbr, qkvI, out);
}

// Round 10
// 261.961 us; speedup vs baseline: 1.3806x; 1.3554x over previous
//
#include <hip/hip_runtime.h>
#include <hip/hip_bf16.h>

// Problem constants (reference: B,K,N,F,H = 20000,10,100000,256,128)
constexpr int B_ = 20000;
constexpr int K_ = 10;
constexpr int N_ = 100000;
constexpr int F_ = 256;
constexpr int H_ = 128;
constexpr int RW = 3 * H_;  // interleaved qkv row width (384 ushorts = 768 B)

typedef __attribute__((ext_vector_type(8))) short bf16x8;
typedef __attribute__((ext_vector_type(4))) float f32x4;

__device__ __forceinline__ unsigned short f2bf(float x) {
  unsigned int u = __builtin_bit_cast(unsigned int, x);
  unsigned int r = u + 0x7fffu + ((u >> 16) & 1u);
  return (unsigned short)(r >> 16);
}

__device__ __forceinline__ float bf2f(unsigned int u16) {
  return __builtin_bit_cast(float, u16 << 16);
}

// RNE pack of two f32 -> 2xbf16 in one dword (lo -> [15:0], hi -> [31:16]).
__device__ __forceinline__ unsigned int cvt_pk_bf16(float lo, float hi) {
  unsigned int r;
  asm("v_cvt_pk_bf16_f32 %0, %1, %2" : "=v"(r) : "v"(lo), "v"(hi));
  return r;
}

__device__ __forceinline__ float fast_tanh(float x) {
  float e = __expf(2.0f * x);
  return 1.0f - 2.0f * __builtin_amdgcn_rcpf(e + 1.0f);
}

// ---------------------------------------------------------------------------
// Prep: weights -> fragment-major bf16 layout (proven correct; unchanged).
// wat2 chunks (p, ks∈8, c∈8), 512 bf16 each: elem(lane,j) = Wa_p[32ks+8(lane>>4)+j][16c+(lane&15)]
// wbt2 chunks (p, c2∈8, ks2∈4):              elem(lane,j) = Wb_p[32ks2+8(lane>>4)+j][16c2+(lane&15)]
// ---------------------------------------------------------------------------
__global__ __launch_bounds__(256) void prep_kernel(
    const float* __restrict__ W1a, const float* __restrict__ W1b,
    const float* __restrict__ W2a, const float* __restrict__ W2b,
    const float* __restrict__ W3a, const float* __restrict__ W3b,
    unsigned short* __restrict__ wat2, unsigned short* __restrict__ wbt2) {
  const float* Wa[3] = {W1a, W2a, W3a};
  const float* Wb[3] = {W1b, W2b, W3b};
  int g = blockIdx.x * 256 + threadIdx.x;
  if (g < 3 * 64 * 512) {
    int chunk = g >> 9;
    int e = g & 511;
    int lane = e >> 3, j = e & 7;
    int c = chunk & 7;
    int ks = (chunk >> 3) & 7;
    int p = chunk >> 6;
    int k = 32 * ks + 8 * (lane >> 4) + j;
    int h = 16 * c + (lane & 15);
    wat2[g] = f2bf(Wa[p][k * H_ + h]);
  } else {
    int g2 = g - 3 * 64 * 512;
    int chunk = g2 >> 9;
    int e = g2 & 511;
    int lane = e >> 3, j = e & 7;
    int ks2 = chunk & 3;
    int c2 = (chunk >> 2) & 7;
    int p = chunk >> 5;
    int k = 32 * ks2 + 8 * (lane >> 4) + j;
    int h2 = 16 * c2 + (lane & 15);
    wbt2[g2] = f2bf(Wb[p][k * H_ + h2]);
  }
}

// ---------------------------------------------------------------------------
// Projections — R10: minimal-block geometry for max concurrency WITH the
// proven R1 skeleton. Evidence synthesis: R1 (50% occ, 8-wave barriers) = 89us
// best; R7 (71% occ, doubled LDS traffic) = 99; R9 (no barriers, 1.4
// waves/SIMD) = 207. Concurrency is the live variable; both prior high-occ
// attempts carried a confound. This round: 2 waves / 128 thr / MT=16.
//   * LDS = 8.4 KB (xs) + 4.4 KB (ts) = 12.8 KB -> 12 blocks/CU = 24
//     waves/CU (75% occ, 6/SIMD) — 3x R1's concurrency.
//   * Barriers are 2-wave rendezvous (cheapest possible s_barrier).
//   * Wave w owns h-tiles {4w..4w+3}: acc[4]/ac2[4], 4 weight loads + 4
//     MFMAs per k-step; the two waves read disjoint weight chunk halves
//     (no duplication within a block). All addressing is the proven
//     R1/R4 layout with hp = 4w+i substituted.
//   * Accepted cost: weight L2 traffic x4 vs R1 (~1.8 GB aggregate);
//     12 co-resident blocks/CU read the same stream (L1/L2-hot).
// ---------------------------------------------------------------------------
constexpr int MT = 16;
constexpr int XS = F_ + 8;  // 264 shorts = 528 B row stride (proven pattern)
constexpr int TS = H_ + 8;  // 136 shorts = 272 B row stride

__global__ __launch_bounds__(128) void proj_kernel(
    const float* __restrict__ E,
    const unsigned short* __restrict__ wat2,
    const unsigned short* __restrict__ wbt2,
    unsigned short* __restrict__ qkvI) {
  __shared__ unsigned short xs[MT * XS];  // 8448 B
  __shared__ unsigned short ts[MT * TS];  // 4352 B

  const int tid = threadIdx.x;
  const int lane = tid & 63;
  const int w = tid >> 6;    // 0..1 : owns h-tiles {4w .. 4w+3}
  const int l15 = lane & 15;
  const int q = lane >> 4;
  const int row0 = blockIdx.x * MT;

  // ---- stage X tile (fp32 -> bf16), coalesced; clamp OOB rows (insurance)
  {
    const float4* Eg = (const float4*)E;
#pragma unroll
    for (int it = 0; it < 8; ++it) {
      int i = tid + 128 * it;
      int r = i >> 6;
      int c4 = i & 63;
      int row = row0 + r;
      if (row >= N_) row = N_ - 1;
      float4 v = Eg[(size_t)row * (F_ / 4) + c4];
      unsigned int lo = cvt_pk_bf16(v.x, v.y);
      unsigned int hi = cvt_pk_bf16(v.z, v.w);
      *(uint2*)&xs[r * XS + c4 * 4] = make_uint2(lo, hi);
    }
  }
  __syncthreads();

  for (int p = 0; p < 3; ++p) {
    const unsigned short* __restrict__ wa = wat2 + p * (64 * 512);
    const unsigned short* __restrict__ wb = wbt2 + p * (32 * 512);

    // ---- layer 1, K=256. acc[i]: h-tile 4w+i, the single node-tile.
    f32x4 acc[4];
#pragma unroll
    for (int i = 0; i < 4; ++i) acc[i] = (f32x4)0.0f;

#pragma unroll
    for (int ks = 0; ks < 8; ++ks) {
      bf16x8 bx = *(const bf16x8*)&xs[l15 * XS + 32 * ks + 8 * q];
#pragma unroll
      for (int i = 0; i < 4; ++i) {
        bf16x8 af = *(const bf16x8*)&wa[(ks * 8 + 4 * w + i) * 512 + lane * 8];
        acc[i] = __builtin_amdgcn_mfma_f32_16x16x32_bf16(af, bx, acc[i], 0, 0, 0);
      }
    }

    // ---- tanh + pack -> ts[node][h] via 8B LDS writes (C->A transpose)
    __syncthreads();  // prior p's ts reads complete (2-wave rendezvous)
#pragma unroll
    for (int i = 0; i < 4; ++i) {
      unsigned int lo = cvt_pk_bf16(fast_tanh(acc[i][0]), fast_tanh(acc[i][1]));
      unsigned int hi = cvt_pk_bf16(fast_tanh(acc[i][2]), fast_tanh(acc[i][3]));
      // value (h = 16*(4w+i)+4q+r, node = l15)
      *(uint2*)&ts[l15 * TS + 16 * (4 * w + i) + 4 * q] = make_uint2(lo, hi);
    }
    __syncthreads();

    // ---- layer 2, K=128. ac2[i]: output h-tile c2 = 4w+i.
    f32x4 ac2[4];
#pragma unroll
    for (int i = 0; i < 4; ++i) ac2[i] = (f32x4)0.0f;

#pragma unroll
    for (int ks2 = 0; ks2 < 4; ++ks2) {
      bf16x8 bt = *(const bf16x8*)&ts[l15 * TS + 32 * ks2 + 8 * q];
#pragma unroll
      for (int i = 0; i < 4; ++i) {
        bf16x8 ab = *(const bf16x8*)&wb[((4 * w + i) * 4 + ks2) * 512 + lane * 8];
        ac2[i] = __builtin_amdgcn_mfma_f32_16x16x32_bf16(ab, bt, ac2[i], 0, 0, 0);
      }
    }

    // ---- store qkv^T: col=node, rows h2 consecutive -> 8B contiguous stores
#pragma unroll
    for (int i = 0; i < 4; ++i) {
      int n = row0 + l15;
      if (n < N_) {
        unsigned int lo = cvt_pk_bf16(ac2[i][0], ac2[i][1]);
        unsigned int hi = cvt_pk_bf16(ac2[i][2], ac2[i][3]);
        *(uint2*)&qkvI[(size_t)n * RW + p * H_ + 16 * (4 * w + i) + 4 * q] =
            make_uint2(lo, hi);
      }
    }
  }
}

// ---------------------------------------------------------------------------
// Phase 2: one WAVE per batch node, gathering from interleaved qkvI
// (768 B contiguous per neighbor). No LDS, no barriers. (Unchanged.)
// ---------------------------------------------------------------------------
__global__ __launch_bounds__(256) void agg_kernel(
    const int* __restrict__ nbr,
    const unsigned short* __restrict__ qkvI,
    float* __restrict__ out) {
  const int lane = threadIdx.x & 63;
  const int wv = threadIdx.x >> 6;
  const int b = blockIdx.x * 4 + wv;
  const int l15 = lane & 15;
  const int kg = lane >> 4;

  const int ni = nbr[b * K_ + (l15 < K_ ? l15 : 0)];
  const size_t nbase = (size_t)ni * RW;

  // scores[i][j] = q_i . k_j
  f32x4 sc = (f32x4)0.0f;
#pragma unroll
  for (int k = 0; k < 4; ++k) {
    const int off = k * 32 + kg * 8;
    bf16x8 qf = *(const bf16x8*)&qkvI[nbase + off];
    bf16x8 kf = *(const bf16x8*)&qkvI[nbase + H_ + off];
    sc = __builtin_amdgcn_mfma_f32_16x16x32_bf16(qf, kf, sc, 0, 0, 0);
  }

  if (l15 >= K_) {
#pragma unroll
    for (int r = 0; r < 4; ++r) sc[r] = -3.0e38f;
  }

  float mx[4], e[4], sm[4];
#pragma unroll
  for (int r = 0; r < 4; ++r) mx[r] = sc[r];
#pragma unroll
  for (int st = 1; st < 16; st <<= 1)
#pragma unroll
    for (int r = 0; r < 4; ++r) mx[r] = fmaxf(mx[r], __shfl_xor(mx[r], st, 16));
#pragma unroll
  for (int r = 0; r < 4; ++r) { e[r] = __expf(sc[r] - mx[r]); sm[r] = e[r]; }
#pragma unroll
  for (int st = 1; st < 16; st <<= 1)
#pragma unroll
    for (int r = 0; r < 4; ++r) sm[r] += __shfl_xor(sm[r], st, 16);

  float cs = 0.0f;
#pragma unroll
  for (int r = 0; r < 4; ++r) {
    float a = e[r] * __builtin_amdgcn_rcpf(sm[r]);
    if (kg * 4 + r >= K_) a = 0.0f;
    cs += a;
  }
  cs += __shfl_xor(cs, 16, 64);
  cs += __shfl_xor(cs, 32, 64);

  float o0 = 0.0f, o1 = 0.0f;
#pragma unroll
  for (int j = 0; j < K_; ++j) {
    const float cj = __shfl(cs, j, 64);
    const int nj = __shfl(ni, j, 64);
    const unsigned int v2 =
        *(const unsigned int*)&qkvI[(size_t)nj * RW + 2 * H_ + 2 * lane];
    o0 = fmaf(cj, bf2f(v2 & 0xffffu), o0);
    o1 = fmaf(cj, bf2f(v2 >> 16), o1);
  }
  *(float2*)&out[(size_t)b * H_ + 2 * lane] = make_float2(o0, o1);
}

extern "C" void kernel_launch(void* const* d_in, const int* in_sizes, int n_in,
                              void* d_out, int out_size, void* d_ws, size_t ws_size,
                              hipStream_t stream) {
  const int* nbr = (const int*)d_in[0];
  const float* E = (const float*)d_in[1];
  const float* W1a = (const float*)d_in[2];
  const float* W1b = (const float*)d_in[3];
  const float* W2a = (const float*)d_in[4];
  const float* W2b = (const float*)d_in[5];
  const float* W3a = (const float*)d_in[6];
  const float* W3b = (const float*)d_in[7];
  float* out = (float*)d_out;

  // workspace: qkvI [N][384] bf16 interleaved = 76.8 MB, then frag-major weights
  unsigned short* qkvI = (unsigned short*)d_ws;
  unsigned short* wat2 = qkvI + (size_t)N_ * RW;
  unsigned short* wbt2 = wat2 + (size_t)3 * 64 * 512;

  prep_kernel<<<(3 * 64 * 512 + 3 * 32 * 512) / 256, 256, 0, stream>>>(
      W1a, W1b, W2a, W2b, W3a, W3b, wat2, wbt2);
  proj_kernel<<<(N_ + MT - 1) / MT, 128, 0, stream>>>(E, wat2, wbt2, qkvI);
  agg_kernel<<<B_ / 4, 256, 0, stream>>>(nbr, qkvI, out);
}